// Round 6
// baseline (324.281 us; speedup 1.0000x reference)
//
#include <hip/hip_runtime.h>

// PCEN: out = (x/( (1e-6+M)^alpha + 1e-6 ) + delta)^r - delta^r
// M = EMA: M[0]=x[0], M[t]=(1-s)M[t-1]+s x[t].  Rows=4096, T=8192.
// R6: SEG=32 (1 block/row), loads force-materialized via empty asm "+v"
// (beats hipcc load-sinking, the R3/R4/R5 bottleneck), nontemporal stores.
// Lookback = 32-elem geometric dot (om^32 ~ 1.6e-7 truncation, far below
// the 3.9e-3 fast-transcendental error floor). tid0 seeds M=x[0] exactly.

#define T_LEN 8192
#define SEG   32
#define LB    32

typedef float v4 __attribute__((ext_vector_type(4)));

__device__ __forceinline__ float fexp2(float x){ return __builtin_amdgcn_exp2f(x); }
__device__ __forceinline__ float flog2(float x){ return __builtin_amdgcn_logf(x); }  // log base 2
__device__ __forceinline__ float frcp (float x){ return __builtin_amdgcn_rcpf(x); }

__global__ __launch_bounds__(256) void pcen_kernel(
    const float* __restrict__ x,
    const float* __restrict__ p_alpha, const float* __restrict__ p_delta,
    const float* __restrict__ p_r,     const float* __restrict__ p_s,
    float* __restrict__ out)
{
    const int tid = threadIdx.x;
    const long long rbase = (long long)blockIdx.x * T_LEN;
    const int t0 = tid * SEG;                 // first owned element in row
    const float* rp = x + rbase;

    // scalar params (uniform -> s_load), issued before the vector loads' wait
    const float alpha_c = fminf(fmaxf(p_alpha[0], 0.01f), 0.99f);
    const float delta_c = fabsf(p_delta[0]) + 1e-6f;
    const float r_c     = fminf(fmaxf(p_r[0], 0.01f), 1.0f);
    const float s       = p_s[0];
    const float om      = 1.0f - s;
    const float dr      = fexp2(r_c * flog2(delta_c));   // delta_c^r_c

    // ---- issue ALL 16 float4 loads, then force materialization ----
    const v4* mp = reinterpret_cast<const v4*>(rp + t0);
    const v4* lp = reinterpret_cast<const v4*>(rp + (t0 ? t0 - LB : 0));
    v4 xq0=mp[0], xq1=mp[1], xq2=mp[2], xq3=mp[3],
       xq4=mp[4], xq5=mp[5], xq6=mp[6], xq7=mp[7];
    v4 lq0=lp[0], lq1=lp[1], lq2=lp[2], lq3=lp[3],
       lq4=lp[4], lq5=lp[5], lq6=lp[6], lq7=lp[7];
    asm volatile("" : "+v"(xq0), "+v"(xq1), "+v"(xq2), "+v"(xq3),
                      "+v"(xq4), "+v"(xq5), "+v"(xq6), "+v"(xq7),
                      "+v"(lq0), "+v"(lq1), "+v"(lq2), "+v"(lq3),
                      "+v"(lq4), "+v"(lq5), "+v"(lq6), "+v"(lq7));

    float xv[32] = {xq0.x,xq0.y,xq0.z,xq0.w, xq1.x,xq1.y,xq1.z,xq1.w,
                    xq2.x,xq2.y,xq2.z,xq2.w, xq3.x,xq3.y,xq3.z,xq3.w,
                    xq4.x,xq4.y,xq4.z,xq4.w, xq5.x,xq5.y,xq5.z,xq5.w,
                    xq6.x,xq6.y,xq6.z,xq6.w, xq7.x,xq7.y,xq7.z,xq7.w};
    float lv[32] = {lq0.x,lq0.y,lq0.z,lq0.w, lq1.x,lq1.y,lq1.z,lq1.w,
                    lq2.x,lq2.y,lq2.z,lq2.w, lq3.x,lq3.y,lq3.z,lq3.w,
                    lq4.x,lq4.y,lq4.z,lq4.w, lq5.x,lq5.y,lq5.z,lq5.w,
                    lq6.x,lq6.y,lq6.z,lq6.w, lq7.x,lq7.y,lq7.z,lq7.w};

    // ---- M_pre ~= M[t0-1]: geometric-weight dot, 8 indep 4-dots + Horner ----
    const float wD = s, wC = s*om, wB = wC*om, wA = wB*om;
    const float om2 = om*om, om4 = om2*om2;
    float c[8];
    #pragma unroll
    for (int g = 0; g < 8; ++g)
        c[g] = fmaf(wA, lv[4*g],
               fmaf(wB, lv[4*g+1],
               fmaf(wC, lv[4*g+2], wD * lv[4*g+3])));
    float acc = c[0];
    #pragma unroll
    for (int g = 1; g < 8; ++g) acc = fmaf(acc, om4, c[g]);
    // tid0: seed so that k=0 FMA yields om*x0+s*x0 = x0 (exact M[0])
    float M = (t0 == 0) ? xv[0] : acc;

    // ---- serial EMA chain (the only inherent dependency: 32 FMAs) ----
    float Mv[32];
    #pragma unroll
    for (int k = 0; k < SEG; ++k) { M = fmaf(om, M, s * xv[k]); Mv[k] = M; }

    // ---- pointwise PCEN, ILP-32 independent transcendental chains ----
    float ov[32];
    #pragma unroll
    for (int i = 0; i < SEG; ++i) {
        float sm   = fexp2(alpha_c * flog2(1e-6f + Mv[i]));
        float base = fmaf(xv[i], frcp(sm + 1e-6f), delta_c);
        ov[i]      = fexp2(r_c * flog2(base)) - dr;
    }

    // ---- 8x nontemporal float4 stores (output never re-read) ----
    v4* dst = reinterpret_cast<v4*>(out + rbase + t0);
    #pragma unroll
    for (int g = 0; g < 8; ++g) {
        v4 o = { ov[4*g], ov[4*g+1], ov[4*g+2], ov[4*g+3] };
        __builtin_nontemporal_store(o, dst + g);
    }
}

extern "C" void kernel_launch(void* const* d_in, const int* in_sizes, int n_in,
                              void* d_out, int out_size, void* d_ws, size_t ws_size,
                              hipStream_t stream) {
    const float* x     = (const float*)d_in[0];
    const float* alpha = (const float*)d_in[1];
    const float* delta = (const float*)d_in[2];
    const float* r     = (const float*)d_in[3];
    const float* s     = (const float*)d_in[4];
    float* out = (float*)d_out;

    const int rows = in_sizes[0] / T_LEN;       // 4096 blocks, one row each
    pcen_kernel<<<rows, 256, 0, stream>>>(x, alpha, delta, r, s, out);
}

// Round 7
// 73.477 us; speedup vs baseline: 4.4134x; 4.4134x over previous
//
#include <hip/hip_runtime.h>

// PCEN: out = (x/( (1e-6+M)^alpha + 1e-6 ) + delta)^r - delta^r
// M = EMA: M[0]=x[0], M[t]=(1-s)M[t-1]+s x[t].  Rows=4096, T=8192.
// R7: the R3-R6 bottleneck was hipcc's VGPR budget: without launch_bounds
// minwaves, it targets 8 waves/SIMD (<=64 VGPR) -> sinks loads (latency-
// bound) or, when pinned via asm, SPILLS to scratch (R6's +263MB writes).
// Fix: __launch_bounds__(256,4) -> 128-VGPR budget, loads stay materialized.
// Also reverted nontemporal stores (partial-line eviction amplified writes).
// Lookback = 32-elem geometric dot (trunc ~ om^32 = 1.6e-7, negligible).

#define T_LEN 8192
#define SEG   32
#define LB    32

typedef float v4 __attribute__((ext_vector_type(4)));

__device__ __forceinline__ float fexp2(float x){ return __builtin_amdgcn_exp2f(x); }
__device__ __forceinline__ float flog2(float x){ return __builtin_amdgcn_logf(x); }  // log base 2
__device__ __forceinline__ float frcp (float x){ return __builtin_amdgcn_rcpf(x); }

__global__ __launch_bounds__(256, 4) void pcen_kernel(
    const float* __restrict__ x,
    const float* __restrict__ p_alpha, const float* __restrict__ p_delta,
    const float* __restrict__ p_r,     const float* __restrict__ p_s,
    float* __restrict__ out)
{
    const int tid = threadIdx.x;
    const long long rbase = (long long)blockIdx.x * T_LEN;
    const int t0 = tid * SEG;                 // first owned element in row
    const float* rp = x + rbase;

    // scalar params (uniform -> s_load), resolved while vector loads fly
    const float alpha_c = fminf(fmaxf(p_alpha[0], 0.01f), 0.99f);
    const float delta_c = fabsf(p_delta[0]) + 1e-6f;
    const float r_c     = fminf(fmaxf(p_r[0], 0.01f), 1.0f);
    const float s       = p_s[0];
    const float om      = 1.0f - s;
    const float dr      = fexp2(r_c * flog2(delta_c));   // delta_c^r_c

    // ---- issue ALL 16 float4 loads, pin them in registers ----
    const v4* mp = reinterpret_cast<const v4*>(rp + t0);
    const v4* lp = reinterpret_cast<const v4*>(rp + (t0 ? t0 - LB : 0));
    v4 xq0=mp[0], xq1=mp[1], xq2=mp[2], xq3=mp[3],
       xq4=mp[4], xq5=mp[5], xq6=mp[6], xq7=mp[7];
    v4 lq0=lp[0], lq1=lp[1], lq2=lp[2], lq3=lp[3],
       lq4=lp[4], lq5=lp[5], lq6=lp[6], lq7=lp[7];
    asm volatile("" : "+v"(xq0), "+v"(xq1), "+v"(xq2), "+v"(xq3),
                      "+v"(xq4), "+v"(xq5), "+v"(xq6), "+v"(xq7),
                      "+v"(lq0), "+v"(lq1), "+v"(lq2), "+v"(lq3),
                      "+v"(lq4), "+v"(lq5), "+v"(lq6), "+v"(lq7));

    float xv[32] = {xq0.x,xq0.y,xq0.z,xq0.w, xq1.x,xq1.y,xq1.z,xq1.w,
                    xq2.x,xq2.y,xq2.z,xq2.w, xq3.x,xq3.y,xq3.z,xq3.w,
                    xq4.x,xq4.y,xq4.z,xq4.w, xq5.x,xq5.y,xq5.z,xq5.w,
                    xq6.x,xq6.y,xq6.z,xq6.w, xq7.x,xq7.y,xq7.z,xq7.w};
    float lv[32] = {lq0.x,lq0.y,lq0.z,lq0.w, lq1.x,lq1.y,lq1.z,lq1.w,
                    lq2.x,lq2.y,lq2.z,lq2.w, lq3.x,lq3.y,lq3.z,lq3.w,
                    lq4.x,lq4.y,lq4.z,lq4.w, lq5.x,lq5.y,lq5.z,lq5.w,
                    lq6.x,lq6.y,lq6.z,lq6.w, lq7.x,lq7.y,lq7.z,lq7.w};

    // ---- M_pre ~= M[t0-1]: geometric-weight dot, 8 indep 4-dots + Horner ----
    const float wD = s, wC = s*om, wB = wC*om, wA = wB*om;
    const float om2 = om*om, om4 = om2*om2;
    float c[8];
    #pragma unroll
    for (int g = 0; g < 8; ++g)
        c[g] = fmaf(wA, lv[4*g],
               fmaf(wB, lv[4*g+1],
               fmaf(wC, lv[4*g+2], wD * lv[4*g+3])));
    float acc = c[0];
    #pragma unroll
    for (int g = 1; g < 8; ++g) acc = fmaf(acc, om4, c[g]);
    // tid0: seed so that k=0 FMA yields om*x0+s*x0 = x0 (exact M[0])
    float M = (t0 == 0) ? xv[0] : acc;

    // ---- serial EMA chain (the only inherent dependency: 32 FMAs) ----
    float Mv[32];
    #pragma unroll
    for (int k = 0; k < SEG; ++k) { M = fmaf(om, M, s * xv[k]); Mv[k] = M; }

    // ---- pointwise PCEN, ILP-32 independent transcendental chains ----
    float ov[32];
    #pragma unroll
    for (int i = 0; i < SEG; ++i) {
        float sm   = fexp2(alpha_c * flog2(1e-6f + Mv[i]));
        float base = fmaf(xv[i], frcp(sm + 1e-6f), delta_c);
        ov[i]      = fexp2(r_c * flog2(base)) - dr;
    }

    // ---- 8x plain float4 stores (L2 write-combines the strided pattern) ----
    v4* dst = reinterpret_cast<v4*>(out + rbase + t0);
    #pragma unroll
    for (int g = 0; g < 8; ++g) {
        v4 o = { ov[4*g], ov[4*g+1], ov[4*g+2], ov[4*g+3] };
        dst[g] = o;
    }
}

extern "C" void kernel_launch(void* const* d_in, const int* in_sizes, int n_in,
                              void* d_out, int out_size, void* d_ws, size_t ws_size,
                              hipStream_t stream) {
    const float* x     = (const float*)d_in[0];
    const float* alpha = (const float*)d_in[1];
    const float* delta = (const float*)d_in[2];
    const float* r     = (const float*)d_in[3];
    const float* s     = (const float*)d_in[4];
    float* out = (float*)d_out;

    const int rows = in_sizes[0] / T_LEN;       // 4096 blocks, one row each
    pcen_kernel<<<rows, 256, 0, stream>>>(x, alpha, delta, r, s, out);
}

// Round 8
// 62.427 us; speedup vs baseline: 5.1946x; 1.1770x over previous
//
#include <hip/hip_runtime.h>
#include <math.h>

// PCEN: out = (x/( (1e-6+M)^alpha + 1e-6 ) + delta)^r - delta^r
// M = EMA: M[0]=x[0], M[t]=(1-s)M[t-1]+s x[t].  Rows=4096, T=8192.
// R8 = R5 (best: 56.6us) + one change: r_c==0.5 -> pow via v_sqrt_f32
// (5 -> 4 transcendental ops/elem). R6/R7 asm-pin experiments regressed
// (load-sinking at high occupancy beats forced materialization); reverted.
// Lookback = 32-elem geometric dot (om^32 ~ 1.6e-7 truncation, negligible).

#define T_LEN 8192
#define SEG   16
#define LB    32

__device__ __forceinline__ float fexp2(float x){ return __builtin_amdgcn_exp2f(x); }
__device__ __forceinline__ float flog2(float x){ return __builtin_amdgcn_logf(x); }  // log base 2
__device__ __forceinline__ float frcp (float x){ return __builtin_amdgcn_rcpf(x); }

__global__ __launch_bounds__(256) void pcen_kernel(
    const float* __restrict__ x,
    const float* __restrict__ p_alpha, const float* __restrict__ p_delta,
    const float* __restrict__ p_r,     const float* __restrict__ p_s,
    float* __restrict__ out)
{
    const int tid = threadIdx.x;
    const int bid = blockIdx.x;
    const int row = bid >> 1;                     // 2 blocks per row
    const int t0  = ((bid & 1) << 12) + tid * SEG; // position of first output in row
    const long long rbase = (long long)row * T_LEN;
    const float* rp = x + rbase;

    const float alpha_c = fminf(fmaxf(p_alpha[0], 0.01f), 0.99f);
    const float delta_c = fabsf(p_delta[0]) + 1e-6f;
    const float r_c     = fminf(fmaxf(p_r[0], 0.01f), 1.0f);
    const float s       = p_s[0];
    const float om      = 1.0f - s;
    const bool  rhalf   = (r_c == 0.5f);
    const float dr      = rhalf ? __builtin_sqrtf(delta_c)
                                : fexp2(r_c * flog2(delta_c));   // delta_c^r_c

    // ---- own 16 inputs -> registers (4x float4, 64B aligned) ----
    float xv[16];
    {
        const float4* mp = reinterpret_cast<const float4*>(rp + t0);
        float4 v0 = mp[0], v1 = mp[1], v2 = mp[2], v3 = mp[3];
        xv[0]=v0.x;  xv[1]=v0.y;  xv[2]=v0.z;  xv[3]=v0.w;
        xv[4]=v1.x;  xv[5]=v1.y;  xv[6]=v1.z;  xv[7]=v1.w;
        xv[8]=v2.x;  xv[9]=v2.y;  xv[10]=v2.z; xv[11]=v2.w;
        xv[12]=v3.x; xv[13]=v3.y; xv[14]=v3.z; xv[15]=v3.w;
    }

    // ---- M_pre ~= M[t0-1] (or identity seed at t0=0) ----
    float Mpre;
    if (t0 == 0) {
        // main-loop k=0 then gives M = om*x0 + s*x0 = x0 (exact M[0] to 1 ulp)
        Mpre = xv[0];
    } else if (t0 == SEG) {
        // exact short scan of x[0..15]
        const float4* lp = reinterpret_cast<const float4*>(rp);
        float4 l0 = lp[0], l1 = lp[1], l2 = lp[2], l3 = lp[3];
        float lv[16] = {l0.x,l0.y,l0.z,l0.w, l1.x,l1.y,l1.z,l1.w,
                        l2.x,l2.y,l2.z,l2.w, l3.x,l3.y,l3.z,l3.w};
        float M = lv[0];
        #pragma unroll
        for (int j = 1; j < 16; ++j) M = fmaf(om, M, s * lv[j]);
        Mpre = M;
    } else {
        // 32-elem lookback: M_pre = sum_j s*om^(31-j) * x[t0-32+j]
        // grouped: 8 independent 4-dots, then 8-term Horner in om^4
        const float4* lp = reinterpret_cast<const float4*>(rp + t0 - LB);
        float4 l0=lp[0], l1=lp[1], l2=lp[2], l3=lp[3],
               l4=lp[4], l5=lp[5], l6=lp[6], l7=lp[7];
        float lv[32] = {l0.x,l0.y,l0.z,l0.w, l1.x,l1.y,l1.z,l1.w,
                        l2.x,l2.y,l2.z,l2.w, l3.x,l3.y,l3.z,l3.w,
                        l4.x,l4.y,l4.z,l4.w, l5.x,l5.y,l5.z,l5.w,
                        l6.x,l6.y,l6.z,l6.w, l7.x,l7.y,l7.z,l7.w};
        const float wD = s;            // weights within group: [s*om^3, s*om^2, s*om, s]
        const float wC = s * om;
        const float wB = wC * om;
        const float wA = wB * om;
        const float om2 = om * om;
        const float om4 = om2 * om2;
        float c[8];
        #pragma unroll
        for (int g = 0; g < 8; ++g)
            c[g] = fmaf(wA, lv[4*g],
                   fmaf(wB, lv[4*g+1],
                   fmaf(wC, lv[4*g+2], wD * lv[4*g+3])));
        float acc = c[0];
        #pragma unroll
        for (int g = 1; g < 8; ++g) acc = fmaf(acc, om4, c[g]);
        Mpre = acc;
    }

    // ---- main EMA chain (16 serial FMAs, the only inherent dependency) ----
    float Mv[16];
    {
        float M = Mpre;
        #pragma unroll
        for (int k = 0; k < SEG; ++k) { M = fmaf(om, M, s * xv[k]); Mv[k] = M; }
    }

    // ---- pointwise PCEN; r==0.5 -> sqrt path (4 trans/elem instead of 5) ----
    float ov[16];
    if (rhalf) {
        #pragma unroll
        for (int i = 0; i < SEG; ++i) {
            float sm   = fexp2(alpha_c * flog2(1e-6f + Mv[i]));
            float base = fmaf(xv[i], frcp(sm + 1e-6f), delta_c);
            ov[i]      = __builtin_sqrtf(base) - dr;
        }
    } else {
        #pragma unroll
        for (int i = 0; i < SEG; ++i) {
            float sm   = fexp2(alpha_c * flog2(1e-6f + Mv[i]));
            float base = fmaf(xv[i], frcp(sm + 1e-6f), delta_c);
            ov[i]      = fexp2(r_c * flog2(base)) - dr;
        }
    }

    // ---- stores: 4x float4, per-thread contiguous ----
    float* dst = out + rbase + t0;
    #pragma unroll
    for (int g = 0; g < 4; ++g)
        *reinterpret_cast<float4*>(dst + 4*g) =
            make_float4(ov[4*g], ov[4*g+1], ov[4*g+2], ov[4*g+3]);
}

extern "C" void kernel_launch(void* const* d_in, const int* in_sizes, int n_in,
                              void* d_out, int out_size, void* d_ws, size_t ws_size,
                              hipStream_t stream) {
    const float* x     = (const float*)d_in[0];
    const float* alpha = (const float*)d_in[1];
    const float* delta = (const float*)d_in[2];
    const float* r     = (const float*)d_in[3];
    const float* s     = (const float*)d_in[4];
    float* out = (float*)d_out;

    const int grid = in_sizes[0] / (SEG * 256);   // 8192 blocks (2 per row)
    pcen_kernel<<<grid, 256, 0, stream>>>(x, alpha, delta, r, s, out);
}

// Round 9
// 50.345 us; speedup vs baseline: 6.4412x; 1.2400x over previous
//
#include <hip/hip_runtime.h>
#include <math.h>

// PCEN: out = (x/( (1e-6+M)^alpha + 1e-6 ) + delta)^r - delta^r
// M = EMA: M[0]=x[0], M[t]=(1-s)M[t-1]+s x[t].  Rows=4096, T=8192.
// R9: wave-parallel scan. Lane i owns elems [4i,4i+4) of a 256-elem tile ->
// ALL global loads/stores are lane-contiguous float4 (memcpy pattern), fixing
// the R5-R8 wall (64B-lane-stride accesses touched 4x the cache lines).
// EMA via: per-lane 4-dot (exact) + 6-step shfl_up weighted scan (exact) +
// 4 per-elem FMAs. Carry crosses tiles via __shfl(m,63). Half-1 of each row
// warms up with one unstored tile (om^256 ~ 1e-54 truncation). Half-0 seeds
// carry=x0 (first FMA is the exact identity om*x0+s*x0=x0).

#define T_LEN 8192
#define TILE  256          // elems per wave-tile (64 lanes x 4)
#define HALF  4096
#define NT    16           // output tiles per half-row

__device__ __forceinline__ float fexp2(float x){ return __builtin_amdgcn_exp2f(x); }
__device__ __forceinline__ float flog2(float x){ return __builtin_amdgcn_logf(x); }  // log base 2
__device__ __forceinline__ float frcp (float x){ return __builtin_amdgcn_rcpf(x); }

__global__ __launch_bounds__(256) void pcen_kernel(
    const float* __restrict__ x,
    const float* __restrict__ p_alpha, const float* __restrict__ p_delta,
    const float* __restrict__ p_r,     const float* __restrict__ p_s,
    float* __restrict__ out)
{
    const int tid  = threadIdx.x;
    const int wave = tid >> 6;
    const int lane = tid & 63;
    const int row  = blockIdx.x * 2 + (wave >> 1);   // 2 rows per block
    const int half = wave & 1;                        // each wave: half a row
    const long long rbase = (long long)row * T_LEN;
    const float* rp = x + rbase + half * HALF + lane * 4;
    float*       op = out + rbase + half * HALF + lane * 4;

    const float alpha_c = fminf(fmaxf(p_alpha[0], 0.01f), 0.99f);
    const float delta_c = fabsf(p_delta[0]) + 1e-6f;
    const float r_c     = fminf(fmaxf(p_r[0], 0.01f), 1.0f);
    const float s       = p_s[0];
    const float om      = 1.0f - s;
    const bool  rhalf   = (r_c == 0.5f);
    const float dr      = rhalf ? __builtin_sqrtf(delta_c)
                                : fexp2(r_c * flog2(delta_c));   // delta_c^r_c

    // local-dot weights: d = s*(om^3 vx + om^2 vy + om vz + vw)
    const float wDl = s, wCl = s*om, wBl = wCl*om, wAl = wBl*om;
    const float om2 = om*om, om4 = om2*om2;

    const int t_first = half ? -1 : 0;   // half-1: one unstored warm-up tile

    // double-buffered, fully coalesced tile loads (independent of carry chain)
    float4 cur = *reinterpret_cast<const float4*>(rp + (long long)t_first * TILE);
    int t1 = t_first + 1; if (t1 > NT - 1) t1 = NT - 1;
    float4 nxt = *reinterpret_cast<const float4*>(rp + (long long)t1 * TILE);

    float carry = half ? 0.0f : __shfl(cur.x, 0, 64);  // exact M[-1] seed

    for (int t = t_first; t < NT; ++t) {
        float4 v = cur;
        cur = nxt;
        int tn = t + 2; if (tn > NT - 1) tn = NT - 1;
        nxt = *reinterpret_cast<const float4*>(rp + (long long)tn * TILE);

        // per-lane exact 4-elem reduction: e = om^4*M_in_contrib + d
        float d = fmaf(wAl, v.x, fmaf(wBl, v.y, fmaf(wCl, v.z, wDl * v.w)));
        float e = (lane == 0) ? fmaf(om4, carry, d) : d;

        // Hillis-Steele inclusive scan of m_i = om4*m_{i-1} + e_i over 64 lanes
        float m = e, w = om4;
        #pragma unroll
        for (int k = 0; k < 6; ++k) {
            float up = __shfl_up(m, 1u << k, 64);
            if (lane >= (1 << k)) m = fmaf(w, up, m);
            w = w * w;
        }
        float Mprev  = __shfl_up(m, 1, 64);
        float Mstart = (lane == 0) ? carry : Mprev;   // M at end of prior lane
        carry = __shfl(m, 63, 64);                    // -> next tile

        if (t >= 0) {
            // recompute per-element M (lane0/tile0/half0: om*x0+s*x0 = x0 exact)
            float M0 = fmaf(om, Mstart, s * v.x);
            float M1 = fmaf(om, M0,     s * v.y);
            float M2 = fmaf(om, M1,     s * v.z);
            float M3 = fmaf(om, M2,     s * v.w);

            float4 o;
            if (rhalf) {
                float s0 = fexp2(alpha_c * flog2(1e-6f + M0));
                float s1 = fexp2(alpha_c * flog2(1e-6f + M1));
                float s2 = fexp2(alpha_c * flog2(1e-6f + M2));
                float s3 = fexp2(alpha_c * flog2(1e-6f + M3));
                o.x = __builtin_sqrtf(fmaf(v.x, frcp(s0 + 1e-6f), delta_c)) - dr;
                o.y = __builtin_sqrtf(fmaf(v.y, frcp(s1 + 1e-6f), delta_c)) - dr;
                o.z = __builtin_sqrtf(fmaf(v.z, frcp(s2 + 1e-6f), delta_c)) - dr;
                o.w = __builtin_sqrtf(fmaf(v.w, frcp(s3 + 1e-6f), delta_c)) - dr;
            } else {
                float s0 = fexp2(alpha_c * flog2(1e-6f + M0));
                float s1 = fexp2(alpha_c * flog2(1e-6f + M1));
                float s2 = fexp2(alpha_c * flog2(1e-6f + M2));
                float s3 = fexp2(alpha_c * flog2(1e-6f + M3));
                o.x = fexp2(r_c * flog2(fmaf(v.x, frcp(s0 + 1e-6f), delta_c))) - dr;
                o.y = fexp2(r_c * flog2(fmaf(v.y, frcp(s1 + 1e-6f), delta_c))) - dr;
                o.z = fexp2(r_c * flog2(fmaf(v.z, frcp(s2 + 1e-6f), delta_c))) - dr;
                o.w = fexp2(r_c * flog2(fmaf(v.w, frcp(s3 + 1e-6f), delta_c))) - dr;
            }
            *reinterpret_cast<float4*>(op + (long long)t * TILE) = o;  // coalesced
        }
    }
}

extern "C" void kernel_launch(void* const* d_in, const int* in_sizes, int n_in,
                              void* d_out, int out_size, void* d_ws, size_t ws_size,
                              hipStream_t stream) {
    const float* x     = (const float*)d_in[0];
    const float* alpha = (const float*)d_in[1];
    const float* delta = (const float*)d_in[2];
    const float* r     = (const float*)d_in[3];
    const float* s     = (const float*)d_in[4];
    float* out = (float*)d_out;

    const int rows = in_sizes[0] / T_LEN;    // 4096
    const int grid = rows / 2;               // 2048 blocks: 4 waves = 2 rows
    pcen_kernel<<<grid, 256, 0, stream>>>(x, alpha, delta, r, s, out);
}